// Round 13
// baseline (125.800 us; speedup 1.0000x reference)
//
#include <hip/hip_runtime.h>
#include <hip/hip_bf16.h>
#include <hip/hip_fp16.h>

// ---------------------------------------------------------------------------
// 2-layer GCN (PyG GCNConv semantics):
//   deg[i]  = in-degree(i) + 1 (self loop);  dinv = rsqrt(deg)
//   hs      = (x*dinv @ W)               (stored fp16; dinv folded into A)
//   out[d]  = dinv[d] * ( sum_{(s,d) in E} hs[s] + hs[d] ) + b    (+ relu L1)
//
// r9 radix-partition build; r10 MFMA GEMMs; r12 reverted agg to proven
// 2-node/wave shape (121.7us). Round 13:
//  (1) fuse agg1+gemm2: aggregate 64 nodes/block into the gemm A-tile in LDS
//      (relu(dinv*gather+b1)*dinv, fp16), then MFMA -> hs2. Kills the 25.6MB
//      HID round-trip + one launch. hs2 goes to a SEPARATE buffer (race).
//  (2) pack hist2/runstart2 into one u32 (len | start<<16) - halves table IO.
// ---------------------------------------------------------------------------

#define NBUCK 800    // buckets of 64 nodes: covers 51200 >= N
#define CHUNK 2048   // edges per presort block
#define STASH 2048   // finish LDS record capacity (mean 1024, sd ~32)

typedef float f32x4 __attribute__((ext_vector_type(4)));
typedef _Float16 f16x8 __attribute__((ext_vector_type(8)));

// ---- per-chunk LDS counting sort; all global writes coalesced -------------
__global__ __launch_bounds__(256) void presort_k(const int* __restrict__ src,
                                                 const int* __restrict__ dst,
                                                 unsigned* __restrict__ rec2,
                                                 unsigned* __restrict__ tab2,
                                                 int E) {
    __shared__ int lh[NBUCK], lscan[NBUCK], cur[NBUCK];
    __shared__ int sred[256];
    __shared__ unsigned srec[CHUNK];
    int t = threadIdx.x;
    int lo = blockIdx.x * CHUNK, hi = min(E, lo + CHUNK);

    for (int i = t; i < NBUCK; i += 256) lh[i] = 0;
    __syncthreads();
    for (int e = lo + t; e < hi; e += 256)
        atomicAdd(&lh[dst[e] >> 6], 1);
    __syncthreads();

    // exclusive scan of lh[800] (4 per thread over padded 1024)
    int base = t * 4;
    int v[4];
    int s = 0;
#pragma unroll
    for (int i = 0; i < 4; ++i) {
        int idx = base + i;
        int c = (idx < NBUCK) ? lh[idx] : 0;
        v[i] = c; s += c;
    }
    sred[t] = s;
    __syncthreads();
#pragma unroll
    for (int off = 1; off < 256; off <<= 1) {
        int x = 0;
        if (t >= off) x = sred[t - off];
        __syncthreads();
        sred[t] += x;
        __syncthreads();
    }
    int run = sred[t] - s;
#pragma unroll
    for (int i = 0; i < 4; ++i) {
        int idx = base + i;
        if (idx < NBUCK) { lscan[idx] = run; cur[idx] = run; }
        run += v[i];
    }
    __syncthreads();

    // place records bucket-sorted in LDS
    for (int e = lo + t; e < hi; e += 256) {
        int d = dst[e];
        int p = atomicAdd(&cur[d >> 6], 1);
        srec[p] = (unsigned)(src[e] & 0xffff) | ((unsigned)d << 16);
    }
    __syncthreads();

    // coalesced writes: sorted records + packed (len | start<<16) table
    int n = hi - lo;
    for (int j = t; j < n; j += 256) rec2[lo + j] = srec[j];
    int hbase = blockIdx.x * NBUCK;
    for (int b = t; b < NBUCK; b += 256)
        tab2[hbase + b] = (unsigned)lh[b] | ((unsigned)lscan[b] << 16);
}

// ---- per-bucket totals (column sums of packed table lengths) --------------
__global__ __launch_bounds__(256) void coltot_k(const unsigned* __restrict__ tab2,
                                                int* __restrict__ btot, int BCNT) {
    __shared__ int sred[256];
    int b = blockIdx.x, t = threadIdx.x;
    int s = 0;
    for (int i = t; i < BCNT; i += 256) s += (int)(tab2[i * NBUCK + b] & 0xffff);
    sred[t] = s;
    __syncthreads();
#pragma unroll
    for (int off = 128; off > 0; off >>= 1) {
        if (t < off) sred[t] += sred[t + off];
        __syncthreads();
    }
    if (t == 0) btot[b] = sred[0];
}

// ---- per-bucket CSR finish: computes own bucketBase prefix from btot,
// gathers runs, bins by node in LDS, coalesced writes --------------------
__global__ __launch_bounds__(256) void finish2_k(const unsigned* __restrict__ rec2,
                                                 const unsigned* __restrict__ tab2,
                                                 const int* __restrict__ btot,
                                                 int* __restrict__ offsets,
                                                 float* __restrict__ dinv,
                                                 unsigned short* __restrict__ adj,
                                                 int BCNT, int N, int E) {
    __shared__ int ncnt[64], ncur[64], nodeOff[64];
    __shared__ int stashCnt;
    __shared__ int sred[256];
    __shared__ unsigned stash[STASH];
    __shared__ unsigned short adjl[STASH];
    int b = blockIdx.x, t = threadIdx.x;
    if (t < 64) { ncnt[t] = 0; ncur[t] = 0; }
    if (t == 0) stashCnt = 0;
    if (b == 0 && t == 0) offsets[N] = E;

    // exclusive prefix of btot[0..b): bucket's base in adj/rec order
    int ps = 0;
    for (int i = t; i < b; i += 256) ps += btot[i];
    sred[t] = ps;
    __syncthreads();
#pragma unroll
    for (int off = 128; off > 0; off >>= 1) {
        if (t < off) sred[t] += sred[t + off];
        __syncthreads();
    }
    int bstart = sred[0];
    __syncthreads();

    // gather this bucket's runs from every chunk; count nodes; stash records
    for (int i = t; i < BCNT; i += 256) {
        unsigned h = tab2[i * NBUCK + b];
        int len = (int)(h & 0xffff);
        if (!len) continue;
        int gbase = i * CHUNK + (int)(h >> 16);
        int sp = atomicAdd(&stashCnt, len);
        for (int k = 0; k < len; ++k) {
            unsigned r = rec2[gbase + k];
            atomicAdd(&ncnt[(r >> 16) & 63], 1);
            if (sp + k < STASH) stash[sp + k] = r;
        }
    }
    __syncthreads();

    if (t == 0) {
        int r = 0;
#pragma unroll
        for (int i = 0; i < 64; ++i) { nodeOff[i] = r; r += ncnt[i]; }
    }
    __syncthreads();

    if (t < 64) {
        int gnode = b * 64 + t;
        if (gnode < N) {
            dinv[gnode] = rsqrtf((float)(ncnt[t] + 1));
            offsets[gnode] = bstart + nodeOff[t];
        }
    }
    __syncthreads();

    int tot = stashCnt;
    if (tot > STASH) tot = STASH;
    for (int j = t; j < tot; j += 256) {
        unsigned r = stash[j];
        int ln = (r >> 16) & 63;
        int p = atomicAdd(&ncur[ln], 1);
        adjl[nodeOff[ln] + p] = (unsigned short)(r & 0xffff);
    }
    __syncthreads();
    for (int j = t; j < tot; j += 256) adj[bstart + j] = adjl[j];  // coalesced
}

// ---- MFMA GEMM: Hout[row][c] = fp16( sum_k (X[row][k]*dinv[row]) * W[k][c] )
// 256 thr / 4 waves, 64 rows x NOUT cols per block, K=128. (layer 1 only now)
template <int NOUT>
__global__ __launch_bounds__(256) void gemm_mfma_k(const float* __restrict__ X,
                                                   const float* __restrict__ W,
                                                   const float* __restrict__ dinv,
                                                   __half* __restrict__ Hout, int M) {
    constexpr int K = 128;
    constexpr int BM = 64;
    constexpr int LDP = K + 8;        // 136 halves = 272B row stride (16B-aligned)
    constexpr int CT = NOUT / 16;
    __shared__ _Float16 xs[BM][LDP];       // A tile (dinv-scaled); reused for C out
    __shared__ _Float16 wsl[NOUT][LDP];    // W column-major: wsl[col][k]

    int t = threadIdx.x;
    int brow = blockIdx.x * BM;

    // ---- stage A = X * dinv (row-scaled), fp16 ----
    for (int i = t; i < BM * (K / 4); i += 256) {
        int row = i / (K / 4), c4 = i % (K / 4);
        int gr = brow + row;
        union { _Float16 h[4]; uint2 u; } pk;
        if (gr < M) {
            float4 v = *(const float4*)(X + (size_t)gr * K + c4 * 4);
            float di = dinv[gr];
            pk.h[0] = (_Float16)(v.x * di);
            pk.h[1] = (_Float16)(v.y * di);
            pk.h[2] = (_Float16)(v.z * di);
            pk.h[3] = (_Float16)(v.w * di);
        } else {
            pk.u = make_uint2(0, 0);
        }
        *(uint2*)&xs[row][c4 * 4] = pk.u;
    }

    // ---- stage W column-major fp16 ----
    for (int i = t; i < K * (NOUT / 4); i += 256) {
        int k = i / (NOUT / 4), c4 = i % (NOUT / 4);
        float4 wv = *(const float4*)(W + (size_t)k * NOUT + c4 * 4);
        wsl[c4 * 4 + 0][k] = (_Float16)wv.x;
        wsl[c4 * 4 + 1][k] = (_Float16)wv.y;
        wsl[c4 * 4 + 2][k] = (_Float16)wv.z;
        wsl[c4 * 4 + 3][k] = (_Float16)wv.w;
    }
    __syncthreads();

    // ---- MFMA main loop ----
    int w = t >> 6, lane = t & 63;
    int lrow = lane & 15;             // A row / B col / D col
    int lko = (lane >> 4) * 8;        // k-offset (same map for A and B)

    f32x4 acc[CT];
#pragma unroll
    for (int c = 0; c < CT; ++c) acc[c] = (f32x4){0.f, 0.f, 0.f, 0.f};

#pragma unroll
    for (int s = 0; s < K / 32; ++s) {
        f16x8 a = *(const f16x8*)&xs[w * 16 + lrow][s * 32 + lko];
#pragma unroll
        for (int c = 0; c < CT; ++c) {
            f16x8 b = *(const f16x8*)&wsl[c * 16 + lrow][s * 32 + lko];
            acc[c] = __builtin_amdgcn_mfma_f32_16x16x32_f16(a, b, acc[c], 0, 0, 0);
        }
    }

    // ---- epilogue: transpose through LDS (reuse xs), coalesced stores ----
    __syncthreads();
#pragma unroll
    for (int c = 0; c < CT; ++c) {
#pragma unroll
        for (int r = 0; r < 4; ++r)
            xs[w * 16 + (lane >> 4) * 4 + r][c * 16 + lrow] = (_Float16)acc[c][r];
    }
    __syncthreads();
    for (int j = t; j < BM * (NOUT / 8); j += 256) {
        int row = j / (NOUT / 8), c8 = j % (NOUT / 8);
        int gr = brow + row;
        if (gr < M)
            *(uint4*)(Hout + (size_t)gr * NOUT + c8 * 8) = *(uint4*)&xs[row][c8 * 8];
    }
}

// fp16 row-fragment loaders: 32 lanes cover one row.
__device__ __forceinline__ void ld_row(const __half* p, float (&f)[4]) {
    uint2 u = *(const uint2*)p;                    // 4 halves, 8B
    const __half2* hp = (const __half2*)&u;
    float2 a = __half22float2(hp[0]);
    float2 b = __half22float2(hp[1]);
    f[0] = a.x; f[1] = a.y; f[2] = b.x; f[3] = b.y;
}
__device__ __forceinline__ void ld_row(const __half* p, float (&f)[2]) {
    float2 a = __half22float2(*(const __half2*)p); // 2 halves, 4B
    f[0] = a.x; f[1] = a.y;
}

// Shared agg inner loop (r10-proven): 8-deep gather unroll, V=4 halves/lane.
__device__ __forceinline__ void agg_edges(const __half* __restrict__ hl,
                                          const unsigned short* __restrict__ adj,
                                          int e0, int e1, float (&acc)[4]) {
    int e = e0;
    for (; e + 8 <= e1; e += 8) {
        int s[8];
#pragma unroll
        for (int j = 0; j < 8; ++j) s[j] = adj[e + j];
        float t[8][4];
#pragma unroll
        for (int j = 0; j < 8; ++j) ld_row(hl + (size_t)s[j] * 128, t[j]);
#pragma unroll
        for (int v = 0; v < 4; ++v)
            acc[v] += ((t[0][v] + t[1][v]) + (t[2][v] + t[3][v])) +
                      ((t[4][v] + t[5][v]) + (t[6][v] + t[7][v]));
    }
    for (; e + 2 <= e1; e += 2) {
        int s0 = adj[e], s1 = adj[e + 1];
        float t0[4], t1[4];
        ld_row(hl + (size_t)s0 * 128, t0);
        ld_row(hl + (size_t)s1 * 128, t1);
#pragma unroll
        for (int v = 0; v < 4; ++v) acc[v] += t0[v] + t1[v];
    }
    if (e < e1) {
        float t0[4];
        ld_row(hl + (size_t)adj[e] * 128, t0);
#pragma unroll
        for (int v = 0; v < 4; ++v) acc[v] += t0[v];
    }
}

// ---- FUSED agg1 + gemm2: block owns 64 nodes. Phase 1: each 32-lane
// half-wave aggregates 8 nodes (same MLP as aggregate_k) and writes
// relu(dinv*gather+b1)*dinv fp16 into the gemm A-tile in LDS. Phase 2:
// MFMA with W2 -> hs2 (separate buffer; H is still being read by peers).
template <int NOUT>  // 64
__global__ __launch_bounds__(256) void agg_gemm_k(const __half* __restrict__ H,
                                                  const int* __restrict__ offsets,
                                                  const unsigned short* __restrict__ adj,
                                                  const float* __restrict__ dinv,
                                                  const float* __restrict__ b1,
                                                  const float* __restrict__ W,
                                                  __half* __restrict__ Hout, int N) {
    constexpr int K = 128;
    constexpr int LDP = K + 8;
    constexpr int CT = NOUT / 16;  // 4
    __shared__ _Float16 xs[64][LDP];
    __shared__ _Float16 wsl[NOUT][LDP];

    int t = threadIdx.x;
    int brow = blockIdx.x * 64;

    // ---- stage W2 column-major fp16 ----
    for (int i = t; i < K * (NOUT / 4); i += 256) {
        int k = i / (NOUT / 4), c4 = i % (NOUT / 4);
        float4 wv = *(const float4*)(W + (size_t)k * NOUT + c4 * 4);
        wsl[c4 * 4 + 0][k] = (_Float16)wv.x;
        wsl[c4 * 4 + 1][k] = (_Float16)wv.y;
        wsl[c4 * 4 + 2][k] = (_Float16)wv.z;
        wsl[c4 * 4 + 3][k] = (_Float16)wv.w;
    }

    // ---- phase 1: aggregate 64 nodes (8 per half-wave) into A tile ----
    int hw = t >> 5, sub = t & 31;
    const __half* hl = H + sub * 4;
#pragma unroll 1
    for (int r = 0; r < 8; ++r) {
        int lr = r * 8 + hw;
        int node = brow + lr;
        union { _Float16 h[4]; uint2 u; } pk;
        if (node < N) {
            float acc[4];
            ld_row(hl + (size_t)node * 128, acc);  // self-loop
            agg_edges(hl, adj, offsets[node], offsets[node + 1], acc);
            float di = dinv[node];
#pragma unroll
            for (int v = 0; v < 4; ++v) {
                float o = acc[v] * di + b1[sub * 4 + v];
                o = fmaxf(o, 0.f);          // relu
                pk.h[v] = (_Float16)(o * di);  // fold next layer's dinv
            }
        } else {
            pk.u = make_uint2(0, 0);
        }
        *(uint2*)&xs[lr][sub * 4] = pk.u;
    }
    __syncthreads();

    // ---- phase 2: MFMA ----
    int w = t >> 6, lane = t & 63;
    int lrow = lane & 15;
    int lko = (lane >> 4) * 8;

    f32x4 acc[CT];
#pragma unroll
    for (int c = 0; c < CT; ++c) acc[c] = (f32x4){0.f, 0.f, 0.f, 0.f};

#pragma unroll
    for (int s = 0; s < K / 32; ++s) {
        f16x8 a = *(const f16x8*)&xs[w * 16 + lrow][s * 32 + lko];
#pragma unroll
        for (int c = 0; c < CT; ++c) {
            f16x8 b = *(const f16x8*)&wsl[c * 16 + lrow][s * 32 + lko];
            acc[c] = __builtin_amdgcn_mfma_f32_16x16x32_f16(a, b, acc[c], 0, 0, 0);
        }
    }

    __syncthreads();
#pragma unroll
    for (int c = 0; c < CT; ++c) {
#pragma unroll
        for (int r = 0; r < 4; ++r)
            xs[w * 16 + (lane >> 4) * 4 + r][c * 16 + lrow] = (_Float16)acc[c][r];
    }
    __syncthreads();
    for (int j = t; j < 64 * (NOUT / 8); j += 256) {
        int row = j / (NOUT / 8), c8 = j % (NOUT / 8);
        int gr = brow + row;
        if (gr < N)
            *(uint4*)(Hout + (size_t)gr * NOUT + c8 * 8) = *(uint4*)&xs[row][c8 * 8];
    }
}

// Pull aggregation (layer 2): 2 nodes per wave, 8-deep unroll; C=64,
// V=2 halves/lane; float output.
__global__ __launch_bounds__(256) void aggregate2_k(const __half* __restrict__ H,
                                                    const int* __restrict__ offsets,
                                                    const unsigned short* __restrict__ adj,
                                                    const float* __restrict__ dinv,
                                                    const float* __restrict__ bias,
                                                    float* __restrict__ out, int n) {
    constexpr int C = 64, V = 2;
    int wave = threadIdx.x >> 6;
    int lane = threadIdx.x & 63;
    int half_id = lane >> 5;
    int sub = lane & 31;
    int node = blockIdx.x * 8 + wave * 2 + half_id;
    if (node >= n) return;

    const __half* hl = H + sub * V;

    float acc[V];
    ld_row(hl + (size_t)node * C, acc);  // self-loop term hs[node]

    int e0 = offsets[node], e1 = offsets[node + 1];
    int e = e0;
    for (; e + 8 <= e1; e += 8) {
        int s[8];
#pragma unroll
        for (int j = 0; j < 8; ++j) s[j] = adj[e + j];
        float t[8][V];
#pragma unroll
        for (int j = 0; j < 8; ++j) ld_row(hl + (size_t)s[j] * C, t[j]);
#pragma unroll
        for (int v = 0; v < V; ++v)
            acc[v] += ((t[0][v] + t[1][v]) + (t[2][v] + t[3][v])) +
                      ((t[4][v] + t[5][v]) + (t[6][v] + t[7][v]));
    }
    for (; e + 2 <= e1; e += 2) {
        int s0 = adj[e], s1 = adj[e + 1];
        float t0[V], t1[V];
        ld_row(hl + (size_t)s0 * C, t0);
        ld_row(hl + (size_t)s1 * C, t1);
#pragma unroll
        for (int v = 0; v < V; ++v) acc[v] += t0[v] + t1[v];
    }
    if (e < e1) {
        float t0[V];
        ld_row(hl + (size_t)adj[e] * C, t0);
#pragma unroll
        for (int v = 0; v < V; ++v) acc[v] += t0[v];
    }

    float di = dinv[node];
    float o0 = acc[0] * di + bias[sub * V + 0];
    float o1 = acc[1] * di + bias[sub * V + 1];
    *(float2*)(out + (size_t)node * C + sub * V) = make_float2(o0, o1);
}

extern "C" void kernel_launch(void* const* d_in, const int* in_sizes, int n_in,
                              void* d_out, int out_size, void* d_ws, size_t ws_size,
                              hipStream_t stream) {
    const float* x = (const float*)d_in[0];
    const int* ei = (const int*)d_in[1];   // harness passes integers as int32
    const float* W1 = (const float*)d_in[2];
    const float* b1 = (const float*)d_in[3];
    const float* W2 = (const float*)d_in[4];
    const float* b2 = (const float*)d_in[5];
    float* out = (float*)d_out;

    const int IN_C = 128, HID_C = 128, OUT_C = 64;
    int N = in_sizes[0] / IN_C;   // 50000
    int E = in_sizes[1] / 2;      // 800000
    const int* src = ei;          // row 0
    const int* dst = ei + E;      // row 1

    int BCNT = (E + CHUNK - 1) / CHUNK;  // 391 presort chunks

    // --- workspace layout ---
    int NP = (N + 255) & ~255;
    int EP = (E + 255) & ~255;
    char* w = (char*)d_ws;
    unsigned* tab2 = (unsigned*)w;  w += (size_t)BCNT * NBUCK * 4;  // len|start<<16
    int* btot = (int*)w;            w += (size_t)(NBUCK + 32) * 4;
    int* offsets = (int*)w;         w += (size_t)(NP + 256) * 4;
    float* dinv = (float*)w;        w += (size_t)NP * 4;
    unsigned* rec2 = (unsigned*)w;  w += (size_t)(BCNT * CHUNK) * 4;
    unsigned short* adj = (unsigned short*)w; w += (size_t)EP * 2;
    __half* H1 = (__half*)w;        w += (size_t)NP * HID_C * 2;  // hs1 (fp16)
    __half* H2 = (__half*)w;        w += (size_t)NP * OUT_C * 2;  // hs2 (fp16)
    (void)ws_size; (void)n_in; (void)out_size;

    presort_k<<<BCNT, 256, 0, stream>>>(src, dst, rec2, tab2, E);
    coltot_k<<<NBUCK, 256, 0, stream>>>(tab2, btot, BCNT);
    finish2_k<<<NBUCK, 256, 0, stream>>>(rec2, tab2, btot,
                                         offsets, dinv, adj, BCNT, N, E);

    // Layer 1 GEMM: hs1 = fp16((x*dinv) @ W1)
    gemm_mfma_k<128><<<(N + 63) / 64, 256, 0, stream>>>(x, W1, dinv, H1, N);

    // Fused: A = relu(dinv*gather(hs1)+b1)*dinv ; hs2 = fp16(A @ W2)
    agg_gemm_k<64><<<(N + 63) / 64, 256, 0, stream>>>(
        H1, offsets, adj, dinv, b1, W2, H2, N);

    // Layer 2 aggregation: out = fp32(dinv*gather(hs2) + b2)
    aggregate2_k<<<(N + 7) / 8, 256, 0, stream>>>(
        H2, offsets, adj, dinv, b2, out, N);
}

// Round 14
// 120.818 us; speedup vs baseline: 1.0412x; 1.0412x over previous
//
#include <hip/hip_runtime.h>
#include <hip/hip_bf16.h>
#include <hip/hip_fp16.h>

// ---------------------------------------------------------------------------
// 2-layer GCN (PyG GCNConv semantics):
//   deg[i]  = in-degree(i) + 1 (self loop);  dinv = rsqrt(deg)
//   hs      = (x*dinv @ W)               (stored fp16; dinv folded into A)
//   out[d]  = dinv[d] * ( sum_{(s,d) in E} hs[s] + hs[d] ) + b    (+ relu L1)
//
// r9 radix-partition build; r10 MFMA GEMMs; r12 = proven 121.7us baseline.
// r13 fusion REGRESSED (agg_gemm 48.5us: LDS capped occupancy 26%, 1.7M bank
// conflicts, barrier serialization of gather tails) -> reverted. This round:
// r12 structure + r13's packed build table (len|start<<16, halves table IO).
// Gather phase needs max wave count; never couple it to LDS-heavy compute.
// ---------------------------------------------------------------------------

#define NBUCK 800    // buckets of 64 nodes: covers 51200 >= N
#define CHUNK 2048   // edges per presort block
#define STASH 2048   // finish LDS record capacity (mean 1024, sd ~32)

typedef float f32x4 __attribute__((ext_vector_type(4)));
typedef _Float16 f16x8 __attribute__((ext_vector_type(8)));

// ---- per-chunk LDS counting sort; all global writes coalesced -------------
__global__ __launch_bounds__(256) void presort_k(const int* __restrict__ src,
                                                 const int* __restrict__ dst,
                                                 unsigned* __restrict__ rec2,
                                                 unsigned* __restrict__ tab2,
                                                 int E) {
    __shared__ int lh[NBUCK], lscan[NBUCK], cur[NBUCK];
    __shared__ int sred[256];
    __shared__ unsigned srec[CHUNK];
    int t = threadIdx.x;
    int lo = blockIdx.x * CHUNK, hi = min(E, lo + CHUNK);

    for (int i = t; i < NBUCK; i += 256) lh[i] = 0;
    __syncthreads();
    for (int e = lo + t; e < hi; e += 256)
        atomicAdd(&lh[dst[e] >> 6], 1);
    __syncthreads();

    // exclusive scan of lh[800] (4 per thread over padded 1024)
    int base = t * 4;
    int v[4];
    int s = 0;
#pragma unroll
    for (int i = 0; i < 4; ++i) {
        int idx = base + i;
        int c = (idx < NBUCK) ? lh[idx] : 0;
        v[i] = c; s += c;
    }
    sred[t] = s;
    __syncthreads();
#pragma unroll
    for (int off = 1; off < 256; off <<= 1) {
        int x = 0;
        if (t >= off) x = sred[t - off];
        __syncthreads();
        sred[t] += x;
        __syncthreads();
    }
    int run = sred[t] - s;
#pragma unroll
    for (int i = 0; i < 4; ++i) {
        int idx = base + i;
        if (idx < NBUCK) { lscan[idx] = run; cur[idx] = run; }
        run += v[i];
    }
    __syncthreads();

    // place records bucket-sorted in LDS
    for (int e = lo + t; e < hi; e += 256) {
        int d = dst[e];
        int p = atomicAdd(&cur[d >> 6], 1);
        srec[p] = (unsigned)(src[e] & 0xffff) | ((unsigned)d << 16);
    }
    __syncthreads();

    // coalesced writes: sorted records + packed (len | start<<16) table
    int n = hi - lo;
    for (int j = t; j < n; j += 256) rec2[lo + j] = srec[j];
    int hbase = blockIdx.x * NBUCK;
    for (int b = t; b < NBUCK; b += 256)
        tab2[hbase + b] = (unsigned)lh[b] | ((unsigned)lscan[b] << 16);
}

// ---- per-bucket totals (column sums of packed table lengths) --------------
__global__ __launch_bounds__(256) void coltot_k(const unsigned* __restrict__ tab2,
                                                int* __restrict__ btot, int BCNT) {
    __shared__ int sred[256];
    int b = blockIdx.x, t = threadIdx.x;
    int s = 0;
    for (int i = t; i < BCNT; i += 256) s += (int)(tab2[i * NBUCK + b] & 0xffff);
    sred[t] = s;
    __syncthreads();
#pragma unroll
    for (int off = 128; off > 0; off >>= 1) {
        if (t < off) sred[t] += sred[t + off];
        __syncthreads();
    }
    if (t == 0) btot[b] = sred[0];
}

// ---- per-bucket CSR finish: computes own bucketBase prefix from btot,
// gathers runs, bins by node in LDS, coalesced writes --------------------
__global__ __launch_bounds__(256) void finish2_k(const unsigned* __restrict__ rec2,
                                                 const unsigned* __restrict__ tab2,
                                                 const int* __restrict__ btot,
                                                 int* __restrict__ offsets,
                                                 float* __restrict__ dinv,
                                                 unsigned short* __restrict__ adj,
                                                 int BCNT, int N, int E) {
    __shared__ int ncnt[64], ncur[64], nodeOff[64];
    __shared__ int stashCnt;
    __shared__ int sred[256];
    __shared__ unsigned stash[STASH];
    __shared__ unsigned short adjl[STASH];
    int b = blockIdx.x, t = threadIdx.x;
    if (t < 64) { ncnt[t] = 0; ncur[t] = 0; }
    if (t == 0) stashCnt = 0;
    if (b == 0 && t == 0) offsets[N] = E;

    // exclusive prefix of btot[0..b): bucket's base in adj/rec order
    int ps = 0;
    for (int i = t; i < b; i += 256) ps += btot[i];
    sred[t] = ps;
    __syncthreads();
#pragma unroll
    for (int off = 128; off > 0; off >>= 1) {
        if (t < off) sred[t] += sred[t + off];
        __syncthreads();
    }
    int bstart = sred[0];
    __syncthreads();

    // gather this bucket's runs from every chunk; count nodes; stash records
    for (int i = t; i < BCNT; i += 256) {
        unsigned h = tab2[i * NBUCK + b];
        int len = (int)(h & 0xffff);
        if (!len) continue;
        int gbase = i * CHUNK + (int)(h >> 16);
        int sp = atomicAdd(&stashCnt, len);
        for (int k = 0; k < len; ++k) {
            unsigned r = rec2[gbase + k];
            atomicAdd(&ncnt[(r >> 16) & 63], 1);
            if (sp + k < STASH) stash[sp + k] = r;
        }
    }
    __syncthreads();

    if (t == 0) {
        int r = 0;
#pragma unroll
        for (int i = 0; i < 64; ++i) { nodeOff[i] = r; r += ncnt[i]; }
    }
    __syncthreads();

    if (t < 64) {
        int gnode = b * 64 + t;
        if (gnode < N) {
            dinv[gnode] = rsqrtf((float)(ncnt[t] + 1));
            offsets[gnode] = bstart + nodeOff[t];
        }
    }
    __syncthreads();

    int tot = stashCnt;
    if (tot > STASH) tot = STASH;
    for (int j = t; j < tot; j += 256) {
        unsigned r = stash[j];
        int ln = (r >> 16) & 63;
        int p = atomicAdd(&ncur[ln], 1);
        adjl[nodeOff[ln] + p] = (unsigned short)(r & 0xffff);
    }
    __syncthreads();
    for (int j = t; j < tot; j += 256) adj[bstart + j] = adjl[j];  // coalesced
}

// ---- MFMA GEMM: Hout[row][c] = fp16( sum_k (X[row][k]*dinv[row]) * W[k][c] )
// 256 thr / 4 waves, 64 rows x NOUT cols per block, K=128.
// Wave w owns rows 16w..16w+15; 16x16x32_f16 MFMA, fp32 accum.
template <int NOUT, bool HALF_IN>
__global__ __launch_bounds__(256) void gemm_mfma_k(const void* __restrict__ Xv,
                                                   const float* __restrict__ W,
                                                   const float* __restrict__ dinv,
                                                   __half* __restrict__ Hout, int M) {
    constexpr int K = 128;
    constexpr int BM = 64;
    constexpr int LDP = K + 8;        // 136 halves = 272B row stride (16B-aligned)
    constexpr int CT = NOUT / 16;     // col tiles: 8 or 4
    __shared__ _Float16 xs[BM][LDP];       // A tile (dinv-scaled); reused for C out
    __shared__ _Float16 wsl[NOUT][LDP];    // W column-major: wsl[col][k]

    int t = threadIdx.x;
    int brow = blockIdx.x * BM;

    // ---- stage A = X * dinv (row-scaled), fp16 ----
    if constexpr (HALF_IN) {
        const __half* X = (const __half*)Xv;
        for (int i = t; i < BM * (K / 8); i += 256) {
            int row = i / (K / 8), c8 = i % (K / 8);
            int gr = brow + row;
            union { _Float16 h[8]; uint4 u; } pk;
            if (gr < M) {
                uint4 u = *(const uint4*)(X + (size_t)gr * K + c8 * 8);
                const __half2* hp = (const __half2*)&u;
                float di = dinv[gr];
#pragma unroll
                for (int j = 0; j < 4; ++j) {
                    float2 f = __half22float2(hp[j]);
                    pk.h[2 * j] = (_Float16)(f.x * di);
                    pk.h[2 * j + 1] = (_Float16)(f.y * di);
                }
            } else {
                pk.u = make_uint4(0, 0, 0, 0);
            }
            *(uint4*)&xs[row][c8 * 8] = pk.u;
        }
    } else {
        const float* X = (const float*)Xv;
        for (int i = t; i < BM * (K / 4); i += 256) {
            int row = i / (K / 4), c4 = i % (K / 4);
            int gr = brow + row;
            union { _Float16 h[4]; uint2 u; } pk;
            if (gr < M) {
                float4 v = *(const float4*)(X + (size_t)gr * K + c4 * 4);
                float di = dinv[gr];
                pk.h[0] = (_Float16)(v.x * di);
                pk.h[1] = (_Float16)(v.y * di);
                pk.h[2] = (_Float16)(v.z * di);
                pk.h[3] = (_Float16)(v.w * di);
            } else {
                pk.u = make_uint2(0, 0);
            }
            *(uint2*)&xs[row][c4 * 4] = pk.u;
        }
    }

    // ---- stage W column-major fp16 (coalesced global read, scattered LDS) ----
    for (int i = t; i < K * (NOUT / 4); i += 256) {
        int k = i / (NOUT / 4), c4 = i % (NOUT / 4);
        float4 wv = *(const float4*)(W + (size_t)k * NOUT + c4 * 4);
        wsl[c4 * 4 + 0][k] = (_Float16)wv.x;
        wsl[c4 * 4 + 1][k] = (_Float16)wv.y;
        wsl[c4 * 4 + 2][k] = (_Float16)wv.z;
        wsl[c4 * 4 + 3][k] = (_Float16)wv.w;
    }
    __syncthreads();

    // ---- MFMA main loop ----
    int w = t >> 6, lane = t & 63;
    int lrow = lane & 15;             // A row / B col / D col
    int lko = (lane >> 4) * 8;        // k-offset (same map for A and B)

    f32x4 acc[CT];
#pragma unroll
    for (int c = 0; c < CT; ++c) acc[c] = (f32x4){0.f, 0.f, 0.f, 0.f};

#pragma unroll
    for (int s = 0; s < K / 32; ++s) {
        f16x8 a = *(const f16x8*)&xs[w * 16 + lrow][s * 32 + lko];
#pragma unroll
        for (int c = 0; c < CT; ++c) {
            f16x8 b = *(const f16x8*)&wsl[c * 16 + lrow][s * 32 + lko];
            acc[c] = __builtin_amdgcn_mfma_f32_16x16x32_f16(a, b, acc[c], 0, 0, 0);
        }
    }

    // ---- epilogue: transpose through LDS (reuse xs), coalesced stores ----
    __syncthreads();  // all xs/wsl reads done
#pragma unroll
    for (int c = 0; c < CT; ++c) {
#pragma unroll
        for (int r = 0; r < 4; ++r)
            xs[w * 16 + (lane >> 4) * 4 + r][c * 16 + lrow] = (_Float16)acc[c][r];
    }
    __syncthreads();
    for (int j = t; j < BM * (NOUT / 8); j += 256) {
        int row = j / (NOUT / 8), c8 = j % (NOUT / 8);
        int gr = brow + row;
        if (gr < M)
            *(uint4*)(Hout + (size_t)gr * NOUT + c8 * 8) = *(uint4*)&xs[row][c8 * 8];
    }
}

// fp16 row-fragment loaders: 32 lanes cover one row.
__device__ __forceinline__ void ld_row(const __half* p, float (&f)[4]) {
    uint2 u = *(const uint2*)p;                    // 4 halves, 8B
    const __half2* hp = (const __half2*)&u;
    float2 a = __half22float2(hp[0]);
    float2 b = __half22float2(hp[1]);
    f[0] = a.x; f[1] = a.y; f[2] = b.x; f[3] = b.y;
}
__device__ __forceinline__ void ld_row(const __half* p, float (&f)[2]) {
    float2 a = __half22float2(*(const __half2*)p); // 2 halves, 4B
    f[0] = a.x; f[1] = a.y;
}

// Pull aggregation: 2 nodes per wave (one per 32-lane half-wave), 8-deep
// gather unroll => up to 16 rows in flight per wave. V = C/32 halves/lane.
// (r10-proven shape; r11 4-rows/instr and r13 fusion both regressed.)
template <int C, bool RELU, typename TOUT>
__global__ __launch_bounds__(256) void aggregate_k(const __half* __restrict__ H,
                                                   const int* __restrict__ offsets,
                                                   const unsigned short* __restrict__ adj,
                                                   const float* __restrict__ dinv,
                                                   const float* __restrict__ bias,
                                                   TOUT* __restrict__ out, int n) {
    constexpr int V = C / 32;
    int wave = threadIdx.x >> 6;
    int lane = threadIdx.x & 63;
    int half_id = lane >> 5;
    int sub = lane & 31;
    int node = blockIdx.x * 8 + wave * 2 + half_id;
    if (node >= n) return;

    const __half* hl = H + sub * V;  // lane-fragment base

    float acc[V];
    ld_row(hl + (size_t)node * C, acc);  // self-loop term hs[node]

    int e0 = offsets[node], e1 = offsets[node + 1];
    int e = e0;

    // main: 8 edges per iter, 8 row-gathers outstanding (x2 nodes per wave)
    for (; e + 8 <= e1; e += 8) {
        int s[8];
#pragma unroll
        for (int j = 0; j < 8; ++j) s[j] = adj[e + j];
        float t[8][V];
#pragma unroll
        for (int j = 0; j < 8; ++j) ld_row(hl + (size_t)s[j] * C, t[j]);
#pragma unroll
        for (int v = 0; v < V; ++v)
            acc[v] += ((t[0][v] + t[1][v]) + (t[2][v] + t[3][v])) +
                      ((t[4][v] + t[5][v]) + (t[6][v] + t[7][v]));
    }
    for (; e + 2 <= e1; e += 2) {
        int s0 = adj[e], s1 = adj[e + 1];
        float t0[V], t1[V];
        ld_row(hl + (size_t)s0 * C, t0);
        ld_row(hl + (size_t)s1 * C, t1);
#pragma unroll
        for (int v = 0; v < V; ++v) acc[v] += t0[v] + t1[v];
    }
    if (e < e1) {
        float t0[V];
        ld_row(hl + (size_t)adj[e] * C, t0);
#pragma unroll
        for (int v = 0; v < V; ++v) acc[v] += t0[v];
    }

    float di = dinv[node];
    float o[V];
#pragma unroll
    for (int v = 0; v < V; ++v) {
        o[v] = acc[v] * di + bias[sub * V + v];
        if (RELU) o[v] = fmaxf(o[v], 0.f);
    }

    if constexpr (sizeof(TOUT) == 2) {  // __half output (hidden layer), V==4
        union { __half2 h[2]; uint2 u; } pk;
        pk.h[0] = __floats2half2_rn(o[0], o[1]);
        pk.h[1] = __floats2half2_rn(o[2], o[3]);
        *(uint2*)((__half*)out + (size_t)node * C + sub * V) = pk.u;
    } else {  // float output (final), V==2
        *(float2*)((float*)out + (size_t)node * C + sub * V) = make_float2(o[0], o[1]);
    }
}

extern "C" void kernel_launch(void* const* d_in, const int* in_sizes, int n_in,
                              void* d_out, int out_size, void* d_ws, size_t ws_size,
                              hipStream_t stream) {
    const float* x = (const float*)d_in[0];
    const int* ei = (const int*)d_in[1];   // harness passes integers as int32
    const float* W1 = (const float*)d_in[2];
    const float* b1 = (const float*)d_in[3];
    const float* W2 = (const float*)d_in[4];
    const float* b2 = (const float*)d_in[5];
    float* out = (float*)d_out;

    const int IN_C = 128, HID_C = 128;
    int N = in_sizes[0] / IN_C;   // 50000
    int E = in_sizes[1] / 2;      // 800000
    const int* src = ei;          // row 0
    const int* dst = ei + E;      // row 1

    int BCNT = (E + CHUNK - 1) / CHUNK;  // 391 presort chunks

    // --- workspace layout ---
    int NP = (N + 255) & ~255;
    int EP = (E + 255) & ~255;
    char* w = (char*)d_ws;
    unsigned* tab2 = (unsigned*)w;  w += (size_t)BCNT * NBUCK * 4;  // len|start<<16
    int* btot = (int*)w;            w += (size_t)(NBUCK + 32) * 4;
    int* offsets = (int*)w;         w += (size_t)(NP + 256) * 4;
    float* dinv = (float*)w;        w += (size_t)NP * 4;
    unsigned* rec2 = (unsigned*)w;  w += (size_t)(BCNT * CHUNK) * 4;
    unsigned short* adj = (unsigned short*)w; w += (size_t)EP * 2;
    __half* H1 = (__half*)w;        w += (size_t)NP * HID_C * 2;  // hs1 / hs2 (reuse)
    __half* HID = (__half*)w;       w += (size_t)NP * HID_C * 2;  // relu'd hidden (fp16)
    (void)ws_size; (void)n_in; (void)out_size;

    presort_k<<<BCNT, 256, 0, stream>>>(src, dst, rec2, tab2, E);
    coltot_k<<<NBUCK, 256, 0, stream>>>(tab2, btot, BCNT);
    finish2_k<<<NBUCK, 256, 0, stream>>>(rec2, tab2, btot,
                                         offsets, dinv, adj, BCNT, N, E);

    // Layer 1: hs1 = fp16((x*dinv) @ W1) ; HID = fp16(relu(dinv*gather + b1))
    gemm_mfma_k<128, false><<<(N + 63) / 64, 256, 0, stream>>>(x, W1, dinv, H1, N);
    aggregate_k<128, true, __half><<<(N + 7) / 8, 256, 0, stream>>>(
        H1, offsets, adj, dinv, b1, HID, N);

    // Layer 2: hs2 = fp16((HID*dinv) @ W2) ; out = fp32(dinv*gather + b2)
    gemm_mfma_k<64, true><<<(N + 63) / 64, 256, 0, stream>>>(HID, W2, dinv, H1, N);
    aggregate_k<64, false, float><<<(N + 7) / 8, 256, 0, stream>>>(
        H1, offsets, adj, dinv, b2, out, N);
}